// Round 1
// 431.489 us; speedup vs baseline: 1.1010x; 1.1010x over previous
//
#include <hip/hip_runtime.h>
#include <math.h>

#define NUM_TREES 20000
#define MAX_DEPTH 8
#define MAX_SIZE  40
#define VOCAB     30000
#define DIM       128
#define TOT       (MAX_DEPTH * MAX_SIZE)      // 320 tokens per tree
#define NGATE     ((MAX_DEPTH - 1) * MAX_SIZE) // 280 gated rows (depths 0..6)

__device__ __forceinline__ double waveSumD(double v) {
    v += __shfl_xor(v, 32);
    v += __shfl_xor(v, 16);
    v += __shfl_xor(v, 8);
    v += __shfl_xor(v, 4);
    v += __shfl_xor(v, 2);
    v += __shfl_xor(v, 1);
    return v;
}

// One packed butterfly for three independent fp64 sums (ILP hides the
// per-step shuffle latency across the three chains).
__device__ __forceinline__ void waveSum3(double& a, double& b, double& c) {
    #pragma unroll
    for (int m = 32; m >= 1; m >>= 1) {
        a += __shfl_xor(a, m);
        b += __shfl_xor(b, m);
        c += __shfl_xor(c, m);
    }
}

// masks may arrive as 1-byte bool or int32; probe word 0 (all-ones input:
// byte layout reads 0x01010101, int32 layout reads 0x00000001).
__device__ __forceinline__ int loadMask(const void* m, size_t idx, bool asByte) {
    return asByte ? (int)((const unsigned char*)m)[idx] : ((const int*)m)[idx];
}

// Phase 0: ts[v] = dot(embedding[v], context_weight) in fp64 (one wave per row)
__global__ __launch_bounds__(256) void tokscore_kernel(
        const float* __restrict__ emb, const float* __restrict__ cw,
        double* __restrict__ ts) {
    int row  = (blockIdx.x * blockDim.x + threadIdx.x) >> 6;
    int lane = threadIdx.x & 63;
    if (row >= VOCAB) return;
    float2 e2 = *(const float2*)(emb + (size_t)row * DIM + lane * 2);
    float2 w2 = *(const float2*)(cw + lane * 2);
    double p = (double)e2.x * (double)w2.x + (double)e2.y * (double)w2.y;
    p = waveSumD(p);
    if (lane == 0) ts[row] = p;
}

// Phase 1+2 fused: fp64 scalar recursion -> 320 coefficients -> weighted
// gather-sum of embedding rows (fp64 accumulate). One block per tree.
// __launch_bounds__(256,8): 8 waves/EU -> VGPR<=64 -> 8 blocks/CU retained.
__global__ __launch_bounds__(256, 8) void encode_kernel(
        const int* __restrict__ tokens, const void* __restrict__ masks,
        const float* __restrict__ emb, const double* __restrict__ ts,
        float* __restrict__ out) {
    __shared__ int           s_tok[TOT];
    __shared__ double        s_e[TOT];
    __shared__ double        s_gc[NGATE];      // sigmoid gate per row, depths 0..6
    __shared__ unsigned char s_val[TOT];
    __shared__ unsigned char s_msk[TOT];
    __shared__ double        s_coef[TOT];
    __shared__ double        s_red[8][DIM];

    const int tree = blockIdx.x;
    const int tid  = threadIdx.x;
    const size_t base = (size_t)tree * TOT;
    const bool mByte = (((const int*)masks)[0] != 1);   // see loadMask comment

    // ---- Phase 1: stage tokens/masks, gather token scores, compute gates.
    // Issue both token/mask loads before the (dependent) ts gathers; the
    // sigmoid gate is computed by the thread that produced s_e[i] (no extra
    // barrier needed).
    {
        const int iA = tid, iB = tid + 256;
        int tA = tokens[base + iA];
        int mA = loadMask(masks, base + iA, mByte);
        int tB = 0, mB = 0;
        if (iB < TOT) {
            tB = tokens[base + iB];
            mB = loadMask(masks, base + iB, mByte);
        }
        int tcA = tA < 0 ? 0 : tA;
        double eA = ts[tcA];
        s_tok[iA] = tcA;
        s_e[iA]   = eA;
        s_msk[iA] = (unsigned char)(mA != 0);
        s_val[iA] = (unsigned char)((mA != 0) && tA >= 0);
        if (iA < NGATE) s_gc[iA] = 1.0 / (1.0 + exp(-eA));
        if (iB < TOT) {
            int tcB = tB < 0 ? 0 : tB;
            double eB = ts[tcB];
            s_tok[iB] = tcB;
            s_e[iB]   = eB;
            s_msk[iB] = (unsigned char)(mB != 0);
            s_val[iB] = (unsigned char)((mB != 0) && tB >= 0);
            if (iB < NGATE) s_gc[iB] = 1.0 / (1.0 + exp(-eB));
        }
    }
    __syncthreads();

    // ---- Phase 2: scalar recursion on wave 0. Per-depth critical path is
    // now: 1 fma -> 1 fp64 exp -> 1 packed butterfly -> rcp + 2 fma.
    //   * ncf via ballot/popcount (SALU) instead of an fp64 butterfly
    //   * gates precomputed in phase 1
    //   * no max-subtraction: |a| <= 8*max|ts| ~ 20, exp(20)=5e8, safe in fp64
    if (tid < 64) {
        const int s = tid;
        const bool inS = s < MAX_SIZE;

        unsigned int valbit = 0, childbit = 0;
        #pragma unroll
        for (int d = 0; d < MAX_DEPTH - 1; ++d) {
            bool mn = inS && s_msk[(d + 1) * MAX_SIZE + s];
            unsigned long long bal = __ballot(mn);
            int nc = (int)__popcll(bal);
            if (nc < 1) nc = 1;
            bool val = inS && s_val[d * MAX_SIZE + s];
            if (val) valbit |= 1u << d;
            if (val && s < nc) childbit |= 1u << d;
        }

        double v7 = (inS && s_val[7 * MAX_SIZE + s]) ? 1.0 : 0.0;
        double e7 = inS ? s_e[7 * MAX_SIZE + s] : 0.0;
        double pw = waveSumD(e7 * v7);

        double cArr[MAX_DEPTH - 1];
        #pragma unroll
        for (int d = MAX_DEPTH - 2; d >= 0; --d) {
            double e  = inS ? s_e[d * MAX_SIZE + s] : 0.0;
            double g  = inS ? s_gc[d * MAX_SIZE + s] : 0.0;
            double cf = ((childbit >> d) & 1) ? g : 0.0;   // gate*child
            double a  = fma(cf, pw, e);
            double ex = ((valbit >> d) & 1) ? exp(a) : 0.0;
            double s0 = ex;            // -> den
            double s1 = ex * cf;       // -> c * den
            double s2 = ex * e;        // -> (sum attn*e) * den
            waveSum3(s0, s1, s2);
            double inv = 1.0 / s0;
            double c   = s1 * inv;
            pw = fma(c, pw, s2 * inv);
            if (inS) s_coef[d * MAX_SIZE + s] = ex * inv;  // attn
            cArr[d] = c;
        }
        double prefix = 1.0;
        #pragma unroll
        for (int d = 0; d <= MAX_DEPTH - 2; ++d) {
            if (inS) s_coef[d * MAX_SIZE + s] *= prefix;
            prefix *= cArr[d];
        }
        if (inS) s_coef[7 * MAX_SIZE + s] = prefix * v7;
    }
    __syncthreads();

    // ---- Phase 3: weighted gather-sum: out[tree] = sum_i coef[i]*emb[tok[i]]
    // 8 groups of 32 lanes; 32 lanes x float4 = one contiguous 512B row read.
    // Branchless + batched (5 rows in flight per group) for memory-level
    // parallelism; coef==0 rows just contribute 0 (token already clamped).
    {
        const int grp = tid >> 5;
        const int col = (tid & 31) << 2;
        double ax = 0.0, ay = 0.0, az = 0.0, aw = 0.0;
        #pragma unroll 1
        for (int jb = 0; jb < 40; jb += 5) {
            double w[5];
            const float4* p[5];
            #pragma unroll
            for (int k = 0; k < 5; ++k) {
                int i = grp + (jb + k) * 8;
                w[k] = s_coef[i];
                p[k] = (const float4*)(emb + (size_t)s_tok[i] * DIM + col);
            }
            float4 v[5];
            #pragma unroll
            for (int k = 0; k < 5; ++k) v[k] = *p[k];
            #pragma unroll
            for (int k = 0; k < 5; ++k) {
                ax += w[k] * (double)v[k].x;
                ay += w[k] * (double)v[k].y;
                az += w[k] * (double)v[k].z;
                aw += w[k] * (double)v[k].w;
            }
        }
        s_red[grp][col + 0] = ax;
        s_red[grp][col + 1] = ay;
        s_red[grp][col + 2] = az;
        s_red[grp][col + 3] = aw;
    }
    __syncthreads();
    if (tid < DIM) {
        double r = 0.0;
        #pragma unroll
        for (int g = 0; g < 8; ++g) r += s_red[g][tid];
        out[(size_t)tree * DIM + tid] = (float)r;
    }
}

extern "C" void kernel_launch(void* const* d_in, const int* in_sizes, int n_in,
                              void* d_out, int out_size, void* d_ws, size_t ws_size,
                              hipStream_t stream) {
    const int*   tokens = (const int*)d_in[0];
    const void*  masks  = d_in[1];
    const float* emb    = (const float*)d_in[2];
    const float* cw     = (const float*)d_in[3];
    float*       out    = (float*)d_out;
    double*      ts     = (double*)d_ws;   // 30000 doubles = 240 KB scratch

    int ts_blocks = (VOCAB * 64 + 255) / 256;   // one wave per vocab row
    tokscore_kernel<<<ts_blocks, 256, 0, stream>>>(emb, cw, ts);
    encode_kernel<<<NUM_TREES, 256, 0, stream>>>(tokens, masks, emb, ts, out);
}

// Round 3
// 416.010 us; speedup vs baseline: 1.1420x; 1.0372x over previous
//
#include <hip/hip_runtime.h>
#include <math.h>

#define NUM_TREES 20000
#define MAX_DEPTH 8
#define MAX_SIZE  40
#define VOCAB     30000
#define DIM       128
#define TOT       (MAX_DEPTH * MAX_SIZE)       // 320 tokens per tree
#define NGATE     ((MAX_DEPTH - 1) * MAX_SIZE) // 280 gated rows (depths 0..6)
#define NTILE     8
#define TILE_ROWS (VOCAB / NTILE)              // 3750 rows = 1.92 MB (L2-resident)

__device__ __forceinline__ double waveSumD(double v) {
    v += __shfl_xor(v, 32);
    v += __shfl_xor(v, 16);
    v += __shfl_xor(v, 8);
    v += __shfl_xor(v, 4);
    v += __shfl_xor(v, 2);
    v += __shfl_xor(v, 1);
    return v;
}

// One packed butterfly for three independent fp64 sums (ILP hides the
// per-step shuffle latency across the three chains).
__device__ __forceinline__ void waveSum3(double& a, double& b, double& c) {
    #pragma unroll
    for (int m = 32; m >= 1; m >>= 1) {
        a += __shfl_xor(a, m);
        b += __shfl_xor(b, m);
        c += __shfl_xor(c, m);
    }
}

// masks may arrive as 1-byte bool or int32; probe word 0 (all-ones input:
// byte layout reads 0x01010101, int32 layout reads 0x00000001).
__device__ __forceinline__ int loadMask(const void* m, size_t idx, bool asByte) {
    return asByte ? (int)((const unsigned char*)m)[idx] : ((const int*)m)[idx];
}

// Phase 0: ts[v] = dot(embedding[v], context_weight) in fp64 (one wave per row)
__global__ __launch_bounds__(256) void tokscore_kernel(
        const float* __restrict__ emb, const float* __restrict__ cw,
        double* __restrict__ ts) {
    int row  = (blockIdx.x * blockDim.x + threadIdx.x) >> 6;
    int lane = threadIdx.x & 63;
    if (row >= VOCAB) return;
    float2 e2 = *(const float2*)(emb + (size_t)row * DIM + lane * 2);
    float2 w2 = *(const float2*)(cw + lane * 2);
    double p = (double)e2.x * (double)w2.x + (double)e2.y * (double)w2.y;
    p = waveSumD(p);
    if (lane == 0) ts[row] = p;
}

// Phase A: fp64 scalar recursion -> 320 coefficients, bucketed by vocab tile
// into workspace (tok as ushort, coef as float). One block per tree.
__global__ __launch_bounds__(256, 8) void phaseA_kernel(
        const int* __restrict__ tokens, const void* __restrict__ masks,
        const double* __restrict__ ts,
        unsigned short* __restrict__ ptok, float* __restrict__ pcoef,
        int* __restrict__ toff) {
    __shared__ int           s_tok[TOT];
    __shared__ double        s_e[TOT];
    __shared__ double        s_gc[NGATE];
    __shared__ unsigned char s_val[TOT];
    __shared__ unsigned char s_msk[TOT];
    __shared__ double        s_coef[TOT];
    __shared__ int           h[NTILE], h2[NTILE], hoff[NTILE + 1];

    const int tree = blockIdx.x;
    const int tid  = threadIdx.x;
    const size_t base = (size_t)tree * TOT;
    const bool mByte = (((const int*)masks)[0] != 1);   // see loadMask comment

    if (tid < NTILE) { h[tid] = 0; h2[tid] = 0; }

    // ---- stage tokens/masks, gather token scores, compute gates.
    {
        const int iA = tid, iB = tid + 256;
        int tA = tokens[base + iA];
        int mA = loadMask(masks, base + iA, mByte);
        int tB = 0, mB = 0;
        if (iB < TOT) {
            tB = tokens[base + iB];
            mB = loadMask(masks, base + iB, mByte);
        }
        int tcA = tA < 0 ? 0 : tA;
        double eA = ts[tcA];
        s_tok[iA] = tcA;
        s_e[iA]   = eA;
        s_msk[iA] = (unsigned char)(mA != 0);
        s_val[iA] = (unsigned char)((mA != 0) && tA >= 0);
        if (iA < NGATE) s_gc[iA] = 1.0 / (1.0 + exp(-eA));
        if (iB < TOT) {
            int tcB = tB < 0 ? 0 : tB;
            double eB = ts[tcB];
            s_tok[iB] = tcB;
            s_e[iB]   = eB;
            s_msk[iB] = (unsigned char)(mB != 0);
            s_val[iB] = (unsigned char)((mB != 0) && tB >= 0);
            if (iB < NGATE) s_gc[iB] = 1.0 / (1.0 + exp(-eB));
        }
    }
    __syncthreads();

    // ---- scalar recursion on wave 0 (validated in round 1).
    if (tid < 64) {
        const int s = tid;
        const bool inS = s < MAX_SIZE;

        unsigned int valbit = 0, childbit = 0;
        #pragma unroll
        for (int d = 0; d < MAX_DEPTH - 1; ++d) {
            bool mn = inS && s_msk[(d + 1) * MAX_SIZE + s];
            unsigned long long bal = __ballot(mn);
            int nc = (int)__popcll(bal);
            if (nc < 1) nc = 1;
            bool val = inS && s_val[d * MAX_SIZE + s];
            if (val) valbit |= 1u << d;
            if (val && s < nc) childbit |= 1u << d;
        }

        double v7 = (inS && s_val[7 * MAX_SIZE + s]) ? 1.0 : 0.0;
        double e7 = inS ? s_e[7 * MAX_SIZE + s] : 0.0;
        double pw = waveSumD(e7 * v7);

        double cArr[MAX_DEPTH - 1];
        #pragma unroll
        for (int d = MAX_DEPTH - 2; d >= 0; --d) {
            double e  = inS ? s_e[d * MAX_SIZE + s] : 0.0;
            double g  = inS ? s_gc[d * MAX_SIZE + s] : 0.0;
            double cf = ((childbit >> d) & 1) ? g : 0.0;   // gate*child
            double a  = fma(cf, pw, e);
            double ex = ((valbit >> d) & 1) ? exp(a) : 0.0;
            double s0 = ex;            // -> den
            double s1 = ex * cf;       // -> c * den
            double s2 = ex * e;        // -> (sum attn*e) * den
            waveSum3(s0, s1, s2);
            double inv = 1.0 / s0;
            double c   = s1 * inv;
            pw = fma(c, pw, s2 * inv);
            if (inS) s_coef[d * MAX_SIZE + s] = ex * inv;  // attn
            cArr[d] = c;
        }
        double prefix = 1.0;
        #pragma unroll
        for (int d = 0; d <= MAX_DEPTH - 2; ++d) {
            if (inS) s_coef[d * MAX_SIZE + s] *= prefix;
            prefix *= cArr[d];
        }
        if (inS) s_coef[7 * MAX_SIZE + s] = prefix * v7;
    }
    __syncthreads();

    // ---- bucket (tok, coef) by vocab tile; drop zero coefficients.
    for (int i = tid; i < TOT; i += 256) {
        if (s_coef[i] != 0.0) atomicAdd(&h[s_tok[i] / TILE_ROWS], 1);
    }
    __syncthreads();
    if (tid == 0) {
        int run = 0;
        #pragma unroll
        for (int t = 0; t < NTILE; ++t) { hoff[t] = run; run += h[t]; }
        hoff[NTILE] = run;
    }
    __syncthreads();
    for (int i = tid; i < TOT; i += 256) {
        if (s_coef[i] != 0.0) {
            int tk = s_tok[i];
            int slot = hoff[tk / TILE_ROWS] + atomicAdd(&h2[tk / TILE_ROWS], 1);
            ptok[base + slot]  = (unsigned short)tk;
            pcoef[base + slot] = (float)s_coef[i];
        }
    }
    if (tid <= NTILE) toff[tree * (NTILE + 1) + tid] = (int)base + hoff[tid];
}

// Phase B: per-tile weighted gather-sum. Launched once per vocab tile so all
// concurrent blocks share one 1.92 MB L2-resident tile. acc is fp64 partials:
// tile 0 initializes, tiles 1..6 accumulate, tile 7 adds + writes out.
__global__ __launch_bounds__(256, 8) void gather_tile_kernel(
        const unsigned short* __restrict__ ptok, const float* __restrict__ pcoef,
        const int* __restrict__ toff, const float* __restrict__ emb,
        double* __restrict__ acc, float* __restrict__ out, int tile) {
    __shared__ unsigned short l_tok[TOT];
    __shared__ float          l_coef[TOT];
    __shared__ double         s_red[8][DIM];

    const int tree = blockIdx.x;
    const int tid  = threadIdx.x;
    const int beg  = toff[tree * (NTILE + 1) + tile];
    const int end  = toff[tree * (NTILE + 1) + tile + 1];
    const int n    = end - beg;

    // Stage this tile's pairs to LDS (coalesced) so the gather chain has a
    // single global load (the L2-hit emb row).
    for (int i = tid; i < n; i += 256) {
        l_tok[i]  = ptok[beg + i];
        l_coef[i] = pcoef[beg + i];
    }
    if (n > 0) __syncthreads();

    const int grp = tid >> 5;
    const int col = (tid & 31) << 2;
    double ax = 0.0, ay = 0.0, az = 0.0, aw = 0.0;
    int j = grp;
    for (; j + 8 < n; j += 16) {        // 2 rows in flight per group
        double w0 = (double)l_coef[j];
        double w1 = (double)l_coef[j + 8];
        const float4 v0 = *(const float4*)(emb + (size_t)l_tok[j]     * DIM + col);
        const float4 v1 = *(const float4*)(emb + (size_t)l_tok[j + 8] * DIM + col);
        ax += w0 * (double)v0.x; ay += w0 * (double)v0.y;
        az += w0 * (double)v0.z; aw += w0 * (double)v0.w;
        ax += w1 * (double)v1.x; ay += w1 * (double)v1.y;
        az += w1 * (double)v1.z; aw += w1 * (double)v1.w;
    }
    for (; j < n; j += 8) {
        double w = (double)l_coef[j];
        const float4 v = *(const float4*)(emb + (size_t)l_tok[j] * DIM + col);
        ax += w * (double)v.x; ay += w * (double)v.y;
        az += w * (double)v.z; aw += w * (double)v.w;
    }
    s_red[grp][col + 0] = ax;
    s_red[grp][col + 1] = ay;
    s_red[grp][col + 2] = az;
    s_red[grp][col + 3] = aw;
    __syncthreads();

    if (tid < DIM) {
        double r = 0.0;
        #pragma unroll
        for (int g = 0; g < 8; ++g) r += s_red[g][tid];
        const size_t o = (size_t)tree * DIM + tid;
        if (tile == 0)               acc[o] = r;
        else if (tile < NTILE - 1)   acc[o] += r;
        else                         out[o] = (float)(acc[o] + r);
    }
}

// ---- Fallback single-kernel path (validated round 1) for small workspaces.
__global__ __launch_bounds__(256, 8) void encode_kernel(
        const int* __restrict__ tokens, const void* __restrict__ masks,
        const float* __restrict__ emb, const double* __restrict__ ts,
        float* __restrict__ out) {
    __shared__ int           s_tok[TOT];
    __shared__ double        s_e[TOT];
    __shared__ double        s_gc[NGATE];
    __shared__ unsigned char s_val[TOT];
    __shared__ unsigned char s_msk[TOT];
    __shared__ double        s_coef[TOT];
    __shared__ double        s_red[8][DIM];

    const int tree = blockIdx.x;
    const int tid  = threadIdx.x;
    const size_t base = (size_t)tree * TOT;
    const bool mByte = (((const int*)masks)[0] != 1);

    {
        const int iA = tid, iB = tid + 256;
        int tA = tokens[base + iA];
        int mA = loadMask(masks, base + iA, mByte);
        int tB = 0, mB = 0;
        if (iB < TOT) {
            tB = tokens[base + iB];
            mB = loadMask(masks, base + iB, mByte);
        }
        int tcA = tA < 0 ? 0 : tA;
        double eA = ts[tcA];
        s_tok[iA] = tcA;
        s_e[iA]   = eA;
        s_msk[iA] = (unsigned char)(mA != 0);
        s_val[iA] = (unsigned char)((mA != 0) && tA >= 0);
        if (iA < NGATE) s_gc[iA] = 1.0 / (1.0 + exp(-eA));
        if (iB < TOT) {
            int tcB = tB < 0 ? 0 : tB;
            double eB = ts[tcB];
            s_tok[iB] = tcB;
            s_e[iB]   = eB;
            s_msk[iB] = (unsigned char)(mB != 0);
            s_val[iB] = (unsigned char)((mB != 0) && tB >= 0);
            if (iB < NGATE) s_gc[iB] = 1.0 / (1.0 + exp(-eB));
        }
    }
    __syncthreads();

    if (tid < 64) {
        const int s = tid;
        const bool inS = s < MAX_SIZE;

        unsigned int valbit = 0, childbit = 0;
        #pragma unroll
        for (int d = 0; d < MAX_DEPTH - 1; ++d) {
            bool mn = inS && s_msk[(d + 1) * MAX_SIZE + s];
            unsigned long long bal = __ballot(mn);
            int nc = (int)__popcll(bal);
            if (nc < 1) nc = 1;
            bool val = inS && s_val[d * MAX_SIZE + s];
            if (val) valbit |= 1u << d;
            if (val && s < nc) childbit |= 1u << d;
        }

        double v7 = (inS && s_val[7 * MAX_SIZE + s]) ? 1.0 : 0.0;
        double e7 = inS ? s_e[7 * MAX_SIZE + s] : 0.0;
        double pw = waveSumD(e7 * v7);

        double cArr[MAX_DEPTH - 1];
        #pragma unroll
        for (int d = MAX_DEPTH - 2; d >= 0; --d) {
            double e  = inS ? s_e[d * MAX_SIZE + s] : 0.0;
            double g  = inS ? s_gc[d * MAX_SIZE + s] : 0.0;
            double cf = ((childbit >> d) & 1) ? g : 0.0;
            double a  = fma(cf, pw, e);
            double ex = ((valbit >> d) & 1) ? exp(a) : 0.0;
            double s0 = ex, s1 = ex * cf, s2 = ex * e;
            waveSum3(s0, s1, s2);
            double inv = 1.0 / s0;
            double c   = s1 * inv;
            pw = fma(c, pw, s2 * inv);
            if (inS) s_coef[d * MAX_SIZE + s] = ex * inv;
            cArr[d] = c;
        }
        double prefix = 1.0;
        #pragma unroll
        for (int d = 0; d <= MAX_DEPTH - 2; ++d) {
            if (inS) s_coef[d * MAX_SIZE + s] *= prefix;
            prefix *= cArr[d];
        }
        if (inS) s_coef[7 * MAX_SIZE + s] = prefix * v7;
    }
    __syncthreads();

    {
        const int grp = tid >> 5;
        const int col = (tid & 31) << 2;
        double ax = 0.0, ay = 0.0, az = 0.0, aw = 0.0;
        #pragma unroll 1
        for (int jb = 0; jb < 40; jb += 5) {
            double w[5];
            const float4* p[5];
            #pragma unroll
            for (int k = 0; k < 5; ++k) {
                int i = grp + (jb + k) * 8;
                w[k] = s_coef[i];
                p[k] = (const float4*)(emb + (size_t)s_tok[i] * DIM + col);
            }
            float4 v[5];
            #pragma unroll
            for (int k = 0; k < 5; ++k) v[k] = *p[k];
            #pragma unroll
            for (int k = 0; k < 5; ++k) {
                ax += w[k] * (double)v[k].x;
                ay += w[k] * (double)v[k].y;
                az += w[k] * (double)v[k].z;
                aw += w[k] * (double)v[k].w;
            }
        }
        s_red[grp][col + 0] = ax;
        s_red[grp][col + 1] = ay;
        s_red[grp][col + 2] = az;
        s_red[grp][col + 3] = aw;
    }
    __syncthreads();
    if (tid < DIM) {
        double r = 0.0;
        #pragma unroll
        for (int g = 0; g < 8; ++g) r += s_red[g][tid];
        out[(size_t)tree * DIM + tid] = (float)r;
    }
}

extern "C" void kernel_launch(void* const* d_in, const int* in_sizes, int n_in,
                              void* d_out, int out_size, void* d_ws, size_t ws_size,
                              hipStream_t stream) {
    const int*   tokens = (const int*)d_in[0];
    const void*  masks  = d_in[1];
    const float* emb    = (const float*)d_in[2];
    const float* cw     = (const float*)d_in[3];
    float*       out    = (float*)d_out;

    // Workspace layout (aligned by construction):
    const size_t o_ts   = 0;
    const size_t o_acc  = o_ts   + (size_t)VOCAB * 8;                 //   240,000
    const size_t o_pc   = o_acc  + (size_t)NUM_TREES * DIM * 8;       // +20.48 MB
    const size_t o_toff = o_pc   + (size_t)NUM_TREES * TOT * 4;       // +25.6 MB
    const size_t o_pt   = o_toff + (size_t)NUM_TREES * (NTILE+1) * 4; // + 0.72 MB
    const size_t need   = o_pt   + (size_t)NUM_TREES * TOT * 2;       // +12.8 MB ~= 60 MB

    double*         ts    = (double*)((char*)d_ws + o_ts);
    double*         acc   = (double*)((char*)d_ws + o_acc);
    float*          pcoef = (float*)((char*)d_ws + o_pc);
    int*            toff  = (int*)((char*)d_ws + o_toff);
    unsigned short* ptok  = (unsigned short*)((char*)d_ws + o_pt);

    int ts_blocks = (VOCAB * 64 + 255) / 256;   // one wave per vocab row
    tokscore_kernel<<<ts_blocks, 256, 0, stream>>>(emb, cw, ts);

    if (ws_size >= need) {
        phaseA_kernel<<<NUM_TREES, 256, 0, stream>>>(tokens, masks, ts,
                                                     ptok, pcoef, toff);
        for (int t = 0; t < NTILE; ++t)
            gather_tile_kernel<<<NUM_TREES, 256, 0, stream>>>(ptok, pcoef, toff,
                                                              emb, acc, out, t);
    } else {
        encode_kernel<<<NUM_TREES, 256, 0, stream>>>(tokens, masks, emb, ts, out);
    }
}

// Round 4
// 390.256 us; speedup vs baseline: 1.2173x; 1.0660x over previous
//
#include <hip/hip_runtime.h>
#include <math.h>

#define NUM_TREES 20000
#define MAX_DEPTH 8
#define MAX_SIZE  40
#define VOCAB     30000
#define DIM       128
#define TOT       (MAX_DEPTH * MAX_SIZE)       // 320 tokens per tree
#define NGATE     ((MAX_DEPTH - 1) * MAX_SIZE) // 280 gated rows (depths 0..6)
#define NTILE     8
#define TILE_ROWS (VOCAB / NTILE)              // 3750 rows = 1.92 MB (L2-resident)
#define TPA       4                            // trees per block, phase A (wave per tree)
#define TPB_B     8                            // trees per block, phase B (group per tree)

__device__ __forceinline__ double waveSumD(double v) {
    v += __shfl_xor(v, 32);
    v += __shfl_xor(v, 16);
    v += __shfl_xor(v, 8);
    v += __shfl_xor(v, 4);
    v += __shfl_xor(v, 2);
    v += __shfl_xor(v, 1);
    return v;
}

// One packed butterfly for three independent fp64 sums (ILP hides the
// per-step shuffle latency across the three chains).
__device__ __forceinline__ void waveSum3(double& a, double& b, double& c) {
    #pragma unroll
    for (int m = 32; m >= 1; m >>= 1) {
        a += __shfl_xor(a, m);
        b += __shfl_xor(b, m);
        c += __shfl_xor(c, m);
    }
}

// masks may arrive as 1-byte bool or int32; probe word 0 (all-ones input:
// byte layout reads 0x01010101, int32 layout reads 0x00000001).
__device__ __forceinline__ int loadMask(const void* m, size_t idx, bool asByte) {
    return asByte ? (int)((const unsigned char*)m)[idx] : ((const int*)m)[idx];
}

// Phase 0: ts[v] = dot(embedding[v], context_weight) in fp64 (one wave per row)
__global__ __launch_bounds__(256) void tokscore_kernel(
        const float* __restrict__ emb, const float* __restrict__ cw,
        double* __restrict__ ts) {
    int row  = (blockIdx.x * blockDim.x + threadIdx.x) >> 6;
    int lane = threadIdx.x & 63;
    if (row >= VOCAB) return;
    float2 e2 = *(const float2*)(emb + (size_t)row * DIM + lane * 2);
    float2 w2 = *(const float2*)(cw + lane * 2);
    double p = (double)e2.x * (double)w2.x + (double)e2.y * (double)w2.y;
    p = waveSumD(p);
    if (lane == 0) ts[row] = p;
}

// Phase A: wave-per-tree fp64 recursion (4 trees/block, all waves active).
// Recursion inputs live in registers; LDS only holds coef/tok for the
// tile-bucketed scatter. Math identical to the round-1-validated kernel.
__global__ __launch_bounds__(256, 6) void phaseA_kernel(
        const int* __restrict__ tokens, const void* __restrict__ masks,
        const double* __restrict__ ts,
        unsigned short* __restrict__ ptok, float* __restrict__ pcoef,
        int* __restrict__ toff) {
    __shared__ double         s_coef[TPA][TOT];
    __shared__ unsigned short s_tk[TPA][TOT];
    __shared__ int            h[TPA][NTILE], h2[TPA][NTILE], hoff[TPA][NTILE + 1];

    const int tid  = threadIdx.x;
    const int w    = tid >> 6;          // wave id = local tree index
    const int s    = tid & 63;          // lane = sibling position
    const int tree = blockIdx.x * TPA + w;
    const size_t base = (size_t)tree * TOT;
    const bool mByte = (((const int*)masks)[0] != 1);   // see loadMask comment
    const bool inS = s < MAX_SIZE;

    if (tid < TPA * NTILE) { ((int*)h)[tid] = 0; ((int*)h2)[tid] = 0; }

    // ---- per-wave load: this tree's tokens/masks/scores into registers.
    double e[MAX_DEPTH];
    unsigned int valbit = 0, mskbit = 0;
    #pragma unroll
    for (int d = 0; d < MAX_DEPTH; ++d) {
        int t = -1, m = 0;
        if (inS) {
            t = tokens[base + d * MAX_SIZE + s];
            m = loadMask(masks, base + d * MAX_SIZE + s, mByte);
        }
        int tc = t < 0 ? 0 : t;
        e[d] = inS ? ts[tc] : 0.0;
        if (inS && m != 0) mskbit |= 1u << d;
        if (inS && m != 0 && t >= 0) valbit |= 1u << d;
        if (inS) s_tk[w][d * MAX_SIZE + s] = (unsigned short)tc;
    }
    double g[MAX_DEPTH - 1];
    #pragma unroll
    for (int d = 0; d < MAX_DEPTH - 1; ++d)
        g[d] = 1.0 / (1.0 + exp(-e[d]));

    unsigned int childbit = 0;
    #pragma unroll
    for (int d = 0; d < MAX_DEPTH - 1; ++d) {
        unsigned long long bal = __ballot((mskbit >> (d + 1)) & 1u);
        int nc = (int)__popcll(bal);
        if (nc < 1) nc = 1;
        if (((valbit >> d) & 1u) && s < nc) childbit |= 1u << d;
    }

    // ---- recursion (identical math to validated version).
    double v7 = ((valbit >> 7) & 1u) ? 1.0 : 0.0;
    double pw = waveSumD(e[7] * v7);

    double cArr[MAX_DEPTH - 1];
    #pragma unroll
    for (int d = MAX_DEPTH - 2; d >= 0; --d) {
        double cf = ((childbit >> d) & 1u) ? g[d] : 0.0;   // gate*child
        double a  = fma(cf, pw, e[d]);
        double ex = ((valbit >> d) & 1u) ? exp(a) : 0.0;
        double s0 = ex;            // -> den
        double s1 = ex * cf;       // -> c * den
        double s2 = ex * e[d];     // -> (sum attn*e) * den
        waveSum3(s0, s1, s2);
        double inv = 1.0 / s0;
        double c   = s1 * inv;
        pw = fma(c, pw, s2 * inv);
        if (inS) s_coef[w][d * MAX_SIZE + s] = ex * inv;   // attn
        cArr[d] = c;
    }
    double prefix = 1.0;
    #pragma unroll
    for (int d = 0; d <= MAX_DEPTH - 2; ++d) {
        if (inS) s_coef[w][d * MAX_SIZE + s] *= prefix;
        prefix *= cArr[d];
    }
    if (inS) s_coef[w][7 * MAX_SIZE + s] = prefix * v7;
    __syncthreads();

    // ---- bucket all 4 trees' (tok, coef) by vocab tile; drop zeros.
    for (int i = tid; i < TPA * TOT; i += 256) {
        int tr = i / TOT, idx = i - tr * TOT;
        if (s_coef[tr][idx] != 0.0)
            atomicAdd(&h[tr][s_tk[tr][idx] / TILE_ROWS], 1);
    }
    __syncthreads();
    if (tid < TPA) {
        int run = 0;
        #pragma unroll
        for (int t = 0; t < NTILE; ++t) { hoff[tid][t] = run; run += h[tid][t]; }
        hoff[tid][NTILE] = run;
    }
    __syncthreads();
    for (int i = tid; i < TPA * TOT; i += 256) {
        int tr = i / TOT, idx = i - tr * TOT;
        double cf = s_coef[tr][idx];
        if (cf != 0.0) {
            int tkk = s_tk[tr][idx];
            size_t tbase = (size_t)(blockIdx.x * TPA + tr) * TOT;
            int slot = hoff[tr][tkk / TILE_ROWS] + atomicAdd(&h2[tr][tkk / TILE_ROWS], 1);
            ptok[tbase + slot]  = (unsigned short)tkk;
            pcoef[tbase + slot] = (float)cf;
        }
    }
    if (tid < TPA * (NTILE + 1)) {
        int tr = tid / (NTILE + 1), t = tid - tr * (NTILE + 1);
        int trg = blockIdx.x * TPA + tr;
        toff[trg * (NTILE + 1) + t] = trg * TOT + hoff[tr][t];
    }
}

// Phase B: per-tile gather, group-per-tree (8 trees/block, zero barriers).
// Each 32-lane group owns one tree: lane covers a float4 column slice, the
// group walks its tree's row list serially (coalesced 512B row reads, all
// L2-hits on the resident tile). acc fp64: tile 0 init, 1..6 RMW, 7 -> out.
__global__ __launch_bounds__(256, 8) void gather_tile_kernel(
        const unsigned short* __restrict__ ptok, const float* __restrict__ pcoef,
        const int* __restrict__ toff, const float* __restrict__ emb,
        double* __restrict__ acc, float* __restrict__ out, int tile) {
    __shared__ unsigned short l_tok[TPB_B * TOT];
    __shared__ float          l_coef[TPB_B * TOT];

    const int tid   = threadIdx.x;
    const int g     = tid >> 5;
    const int lane  = tid & 31;
    const int tree0 = blockIdx.x * TPB_B;

    // Uniform loads (L1-broadcast) of all 8 trees' ranges; local prefix.
    int ns[TPB_B], begs[TPB_B];
    #pragma unroll
    for (int t = 0; t < TPB_B; ++t) {
        int b = toff[(tree0 + t) * (NTILE + 1) + tile];
        int e = toff[(tree0 + t) * (NTILE + 1) + tile + 1];
        begs[t] = b; ns[t] = e - b;
    }
    int off = 0;
    #pragma unroll
    for (int t = 0; t < TPB_B; ++t) off += (t < g) ? ns[t] : 0;

    const int n   = ns[g];
    const int beg = begs[g];
    // Stage own slice (same wave writes & reads -> compiler's lgkmcnt
    // ordering suffices; slices are disjoint across groups -> no barrier).
    for (int i = lane; i < n; i += 32) {
        l_tok[off + i]  = ptok[beg + i];
        l_coef[off + i] = pcoef[beg + i];
    }

    const int col = lane << 2;
    double a0 = 0.0, a1 = 0.0, a2 = 0.0, a3 = 0.0;
    int j = 0;
    for (; j + 2 <= n; j += 2) {
        double w0 = (double)l_coef[off + j];
        double w1 = (double)l_coef[off + j + 1];
        const float4 v0 = *(const float4*)(emb + (size_t)l_tok[off + j]     * DIM + col);
        const float4 v1 = *(const float4*)(emb + (size_t)l_tok[off + j + 1] * DIM + col);
        a0 += w0 * (double)v0.x; a1 += w0 * (double)v0.y;
        a2 += w0 * (double)v0.z; a3 += w0 * (double)v0.w;
        a0 += w1 * (double)v1.x; a1 += w1 * (double)v1.y;
        a2 += w1 * (double)v1.z; a3 += w1 * (double)v1.w;
    }
    if (j < n) {
        double w = (double)l_coef[off + j];
        const float4 v = *(const float4*)(emb + (size_t)l_tok[off + j] * DIM + col);
        a0 += w * (double)v.x; a1 += w * (double)v.y;
        a2 += w * (double)v.z; a3 += w * (double)v.w;
    }

    const size_t ob = (size_t)(tree0 + g) * DIM + col;
    if (tile == 0) {
        *(double2*)(acc + ob)     = make_double2(a0, a1);
        *(double2*)(acc + ob + 2) = make_double2(a2, a3);
    } else if (tile < NTILE - 1) {
        double2 p0 = *(const double2*)(acc + ob);
        double2 p1 = *(const double2*)(acc + ob + 2);
        *(double2*)(acc + ob)     = make_double2(p0.x + a0, p0.y + a1);
        *(double2*)(acc + ob + 2) = make_double2(p1.x + a2, p1.y + a3);
    } else {
        double2 p0 = *(const double2*)(acc + ob);
        double2 p1 = *(const double2*)(acc + ob + 2);
        *(float4*)(out + ob) = make_float4((float)(p0.x + a0), (float)(p0.y + a1),
                                           (float)(p1.x + a2), (float)(p1.y + a3));
    }
}

// ---- Fallback single-kernel path (validated round 1) for small workspaces.
__global__ __launch_bounds__(256, 8) void encode_kernel(
        const int* __restrict__ tokens, const void* __restrict__ masks,
        const float* __restrict__ emb, const double* __restrict__ ts,
        float* __restrict__ out) {
    __shared__ int           s_tok[TOT];
    __shared__ double        s_e[TOT];
    __shared__ double        s_gc[NGATE];
    __shared__ unsigned char s_val[TOT];
    __shared__ unsigned char s_msk[TOT];
    __shared__ double        s_coef[TOT];
    __shared__ double        s_red[8][DIM];

    const int tree = blockIdx.x;
    const int tid  = threadIdx.x;
    const size_t base = (size_t)tree * TOT;
    const bool mByte = (((const int*)masks)[0] != 1);

    {
        const int iA = tid, iB = tid + 256;
        int tA = tokens[base + iA];
        int mA = loadMask(masks, base + iA, mByte);
        int tB = 0, mB = 0;
        if (iB < TOT) {
            tB = tokens[base + iB];
            mB = loadMask(masks, base + iB, mByte);
        }
        int tcA = tA < 0 ? 0 : tA;
        double eA = ts[tcA];
        s_tok[iA] = tcA;
        s_e[iA]   = eA;
        s_msk[iA] = (unsigned char)(mA != 0);
        s_val[iA] = (unsigned char)((mA != 0) && tA >= 0);
        if (iA < NGATE) s_gc[iA] = 1.0 / (1.0 + exp(-eA));
        if (iB < TOT) {
            int tcB = tB < 0 ? 0 : tB;
            double eB = ts[tcB];
            s_tok[iB] = tcB;
            s_e[iB]   = eB;
            s_msk[iB] = (unsigned char)(mB != 0);
            s_val[iB] = (unsigned char)((mB != 0) && tB >= 0);
            if (iB < NGATE) s_gc[iB] = 1.0 / (1.0 + exp(-eB));
        }
    }
    __syncthreads();

    if (tid < 64) {
        const int s = tid;
        const bool inS = s < MAX_SIZE;

        unsigned int valbit = 0, childbit = 0;
        #pragma unroll
        for (int d = 0; d < MAX_DEPTH - 1; ++d) {
            bool mn = inS && s_msk[(d + 1) * MAX_SIZE + s];
            unsigned long long bal = __ballot(mn);
            int nc = (int)__popcll(bal);
            if (nc < 1) nc = 1;
            bool val = inS && s_val[d * MAX_SIZE + s];
            if (val) valbit |= 1u << d;
            if (val && s < nc) childbit |= 1u << d;
        }

        double v7 = (inS && s_val[7 * MAX_SIZE + s]) ? 1.0 : 0.0;
        double e7 = inS ? s_e[7 * MAX_SIZE + s] : 0.0;
        double pw = waveSumD(e7 * v7);

        double cArr[MAX_DEPTH - 1];
        #pragma unroll
        for (int d = MAX_DEPTH - 2; d >= 0; --d) {
            double e  = inS ? s_e[d * MAX_SIZE + s] : 0.0;
            double gg = inS ? s_gc[d * MAX_SIZE + s] : 0.0;
            double cf = ((childbit >> d) & 1) ? gg : 0.0;
            double a  = fma(cf, pw, e);
            double ex = ((valbit >> d) & 1) ? exp(a) : 0.0;
            double s0 = ex, s1 = ex * cf, s2 = ex * e;
            waveSum3(s0, s1, s2);
            double inv = 1.0 / s0;
            double c   = s1 * inv;
            pw = fma(c, pw, s2 * inv);
            if (inS) s_coef[d * MAX_SIZE + s] = ex * inv;
            cArr[d] = c;
        }
        double prefix = 1.0;
        #pragma unroll
        for (int d = 0; d <= MAX_DEPTH - 2; ++d) {
            if (inS) s_coef[d * MAX_SIZE + s] *= prefix;
            prefix *= cArr[d];
        }
        if (inS) s_coef[7 * MAX_SIZE + s] = prefix * v7;
    }
    __syncthreads();

    {
        const int grp = tid >> 5;
        const int col = (tid & 31) << 2;
        double ax = 0.0, ay = 0.0, az = 0.0, aw = 0.0;
        #pragma unroll 1
        for (int jb = 0; jb < 40; jb += 5) {
            double w[5];
            const float4* p[5];
            #pragma unroll
            for (int k = 0; k < 5; ++k) {
                int i = grp + (jb + k) * 8;
                w[k] = s_coef[i];
                p[k] = (const float4*)(emb + (size_t)s_tok[i] * DIM + col);
            }
            float4 v[5];
            #pragma unroll
            for (int k = 0; k < 5; ++k) v[k] = *p[k];
            #pragma unroll
            for (int k = 0; k < 5; ++k) {
                ax += w[k] * (double)v[k].x;
                ay += w[k] * (double)v[k].y;
                az += w[k] * (double)v[k].z;
                aw += w[k] * (double)v[k].w;
            }
        }
        s_red[grp][col + 0] = ax;
        s_red[grp][col + 1] = ay;
        s_red[grp][col + 2] = az;
        s_red[grp][col + 3] = aw;
    }
    __syncthreads();
    if (tid < DIM) {
        double r = 0.0;
        #pragma unroll
        for (int g = 0; g < 8; ++g) r += s_red[g][tid];
        out[(size_t)tree * DIM + tid] = (float)r;
    }
}

extern "C" void kernel_launch(void* const* d_in, const int* in_sizes, int n_in,
                              void* d_out, int out_size, void* d_ws, size_t ws_size,
                              hipStream_t stream) {
    const int*   tokens = (const int*)d_in[0];
    const void*  masks  = d_in[1];
    const float* emb    = (const float*)d_in[2];
    const float* cw     = (const float*)d_in[3];
    float*       out    = (float*)d_out;

    // Workspace layout (aligned by construction):
    const size_t o_ts   = 0;
    const size_t o_acc  = o_ts   + (size_t)VOCAB * 8;                 //   240,000
    const size_t o_pc   = o_acc  + (size_t)NUM_TREES * DIM * 8;       // +20.48 MB
    const size_t o_toff = o_pc   + (size_t)NUM_TREES * TOT * 4;       // +25.6 MB
    const size_t o_pt   = o_toff + (size_t)NUM_TREES * (NTILE+1) * 4; // + 0.72 MB
    const size_t need   = o_pt   + (size_t)NUM_TREES * TOT * 2;       // +12.8 MB ~= 60 MB

    double*         ts    = (double*)((char*)d_ws + o_ts);
    double*         acc   = (double*)((char*)d_ws + o_acc);
    float*          pcoef = (float*)((char*)d_ws + o_pc);
    int*            toff  = (int*)((char*)d_ws + o_toff);
    unsigned short* ptok  = (unsigned short*)((char*)d_ws + o_pt);

    int ts_blocks = (VOCAB * 64 + 255) / 256;   // one wave per vocab row
    tokscore_kernel<<<ts_blocks, 256, 0, stream>>>(emb, cw, ts);

    if (ws_size >= need) {
        phaseA_kernel<<<NUM_TREES / TPA, 256, 0, stream>>>(tokens, masks, ts,
                                                           ptok, pcoef, toff);
        for (int t = 0; t < NTILE; ++t)
            gather_tile_kernel<<<NUM_TREES / TPB_B, 256, 0, stream>>>(
                ptok, pcoef, toff, emb, acc, out, t);
    } else {
        encode_kernel<<<NUM_TREES, 256, 0, stream>>>(tokens, masks, emb, ts, out);
    }
}